// Round 8
// baseline (221.081 us; speedup 1.0000x reference)
//
#include <hip/hip_runtime.h>
#include <hip/hip_bf16.h>

typedef __attribute__((ext_vector_type(8))) short short8;
typedef __attribute__((ext_vector_type(4))) float f32x4;

#define N_PROP 512
#define DHID   1024
#define KFLAT  50176
#define SM_SCALE 0.03125f  /* 1/sqrt(1024) */

__device__ inline short f2bf(float x) {
  __hip_bfloat16 b = __float2bfloat16(x);
  return __builtin_bit_cast(short, b);
}
__device__ inline float bf2f(unsigned short u) {
  unsigned int x = (unsigned int)u << 16;
  return __builtin_bit_cast(float, x);
}

// Raw barrier WITHOUT the compiler's vmcnt(0) drain (T4-lite): lgkmcnt(0)
// orders LDS writes/reads across the barrier; global loads stay in flight
// and are awaited later by their register consumers. asm "memory" clobbers
// pin memory ops on both sides of the barrier.
__device__ inline void pinned_bar() {
  asm volatile("s_waitcnt lgkmcnt(0)" ::: "memory");
  __builtin_amdgcn_s_barrier();
  asm volatile("" ::: "memory");
}

// ---------------- fc1: 256x256 tile, 16 waves, BK=32, XOR-swizzled bf16 LDS --
// parts[y] = A(256-rows) @ B(256-rows)^T over klen=1568 (=49*32, uniform).
// LDS rows are 32 shorts (64B, no pad); 16B chunk c of row r lives at
// phys = c ^ ((r>>1)&3). Verified: reads and writes are <=2-way per 16-lane
// quarter (free). One raw barrier per K-step; prefetch (t+2) stays in flight
// across it (the round-7 __syncthreads drained vmcnt -> 6100 cyc/step).
__global__ __launch_bounds__(1024, 4)
void gemm_fc1(const float* __restrict__ A, const float* __restrict__ B,
              __hip_bfloat16* __restrict__ parts)
{
  constexpr int BK = 32;
  constexpr int KLEN = 1568, NT = KLEN / BK;   // 49
  __shared__ short sA[2][256 * 32];            // 16 KB per buf
  __shared__ short sB[2][256 * 32];            // 64 KB total

  // bijective XCD swizzle, slice-major: XCD j gets 4 consecutive K-slices.
  const int n = gridDim.x;
  int lid = blockIdx.x;
  lid = (lid & 7) * (n >> 3) + (lid >> 3);
  const int y    = lid >> 3;           // 32 slices
  const int tile = lid & 7;
  const int tm = tile >> 2;            // 2 M-tiles
  const int tn = tile & 3;             // 4 N-tiles

  const int k0 = y * KLEN;

  const int tid  = threadIdx.x;
  const int lane = tid & 63;
  const int wid  = tid >> 6;           // 16 waves
  const int wr = wid >> 2, wc = wid & 3;
  const int l16 = lane & 15, kq = lane >> 4;

  const float* Ab = A + (size_t)(tm * 256) * KFLAT;
  const float* Bb = B + (size_t)(tn * 256) * KFLAT;

  // staging: 256x32 fp32 per matrix = 8 floats/thread.
  const int srow = tid >> 2;           // 256 rows
  const int sc   = tid & 3;            // logical 8-float chunk
  const int sphys = sc ^ ((srow >> 1) & 3);    // swizzled LDS chunk

  f32x4 acc[4][4];
  #pragma unroll
  for (int i = 0; i < 4; ++i)
    #pragma unroll
    for (int j = 0; j < 4; ++j)
      acc[i][j] = (f32x4){0.f, 0.f, 0.f, 0.f};

  float4 ra0, ra1, rb0, rb1;

  auto loadAB = [&](int kk) {
    const float* pa = Ab + (size_t)srow * KFLAT + kk + sc * 8;
    const float* pb = Bb + (size_t)srow * KFLAT + kk + sc * 8;
    ra0 = *(const float4*)pa; ra1 = *(const float4*)(pa + 4);
    rb0 = *(const float4*)pb; rb1 = *(const float4*)(pb + 4);
  };
  auto storeAB = [&](int b) {
    short8 s;
    s[0]=f2bf(ra0.x); s[1]=f2bf(ra0.y); s[2]=f2bf(ra0.z); s[3]=f2bf(ra0.w);
    s[4]=f2bf(ra1.x); s[5]=f2bf(ra1.y); s[6]=f2bf(ra1.z); s[7]=f2bf(ra1.w);
    *(short8*)&sA[b][srow * 32 + sphys * 8] = s;
    s[0]=f2bf(rb0.x); s[1]=f2bf(rb0.y); s[2]=f2bf(rb0.z); s[3]=f2bf(rb0.w);
    s[4]=f2bf(rb1.x); s[5]=f2bf(rb1.y); s[6]=f2bf(rb1.z); s[7]=f2bf(rb1.w);
    *(short8*)&sB[b][srow * 32 + sphys * 8] = s;
  };
  auto compute = [&](int b) {
    short8 af[4], bf[4];
    #pragma unroll
    for (int i = 0; i < 4; ++i) {
      int R  = wr * 64 + i * 16 + l16;
      int ph = kq ^ ((R >> 1) & 3);
      af[i] = *(short8*)&sA[b][R * 32 + ph * 8];
    }
    #pragma unroll
    for (int j = 0; j < 4; ++j) {
      int R  = wc * 64 + j * 16 + l16;
      int ph = kq ^ ((R >> 1) & 3);
      bf[j] = *(short8*)&sB[b][R * 32 + ph * 8];
    }
    #pragma unroll
    for (int i = 0; i < 4; ++i)
      #pragma unroll
      for (int j = 0; j < 4; ++j)
        acc[i][j] = __builtin_amdgcn_mfma_f32_16x16x32_bf16(af[i], bf[j], acc[i][j], 0, 0, 0);
  };

  // prologue: tile0 -> buf0; issue loads for tile1.
  loadAB(k0);
  storeAB(0);
  loadAB(k0 + BK);
  pinned_bar();

  int cur = 0;
  for (int t = 0; t < NT; ++t) {
    if (t + 1 < NT) {
      storeAB(cur ^ 1);                           // waits only its own loads
      if (t + 2 < NT) loadAB(k0 + (t + 2) * BK);  // in flight across barrier
    }
    compute(cur);
    pinned_bar();                                 // no vmcnt drain
    cur ^= 1;
  }

  __hip_bfloat16* P = parts + (size_t)y * (N_PROP * DHID);
  const int crow0 = tm * 256 + wr * 64;
  const int ccol0 = tn * 256 + wc * 64;
  #pragma unroll
  for (int i = 0; i < 4; ++i)
    #pragma unroll
    for (int j = 0; j < 4; ++j)
      #pragma unroll
      for (int e = 0; e < 4; ++e) {
        int r = crow0 + i * 16 + kq * 4 + e;
        int c = ccol0 + j * 16 + l16;
        P[(size_t)r * DHID + c] = __float2bfloat16(acc[i][j][e]);
      }
}

// ---------------- generic NT GEMM (small ops) — raw barriers this round ----
template<int BM, int BN, int BK, int MINW>
__global__ __launch_bounds__(256, MINW)
void gemm_nt(const float* __restrict__ A, int lda,
             const float* __restrict__ B1, const float* __restrict__ B2, int ldb,
             float* __restrict__ C, __hip_bfloat16* __restrict__ Cb, int ldc,
             int tiles_per_slice, int tiles_n,
             int klen, int ktot,
             size_t c_split_stride, size_t c_z_stride,
             const float* __restrict__ bias1, const float* __restrict__ bias2,
             const float* __restrict__ res1, const float* __restrict__ res2,
             float* __restrict__ Ct, int ldct,
             int do_relu)
{
  constexpr int BKP = BK + 8;
  constexpr int WM = BM / 2, WN = BN / 2;
  constexpr int FM = WM / 16, FN = WN / 16;
  constexpr int NCH = BK / 8;
  constexpr int CHA = (BM * BK) / (8 * 256);
  constexpr int CHB = (BN * BK) / (8 * 256);

  __shared__ short As[BM * BKP];
  __shared__ short Bs[BN * BKP];

  const int n = gridDim.x;
  int lid = blockIdx.x;
  lid = (lid & 7) * (n >> 3) + (lid >> 3);

  const int y    = lid / tiles_per_slice;
  const int tile = lid % tiles_per_slice;
  const int tm = tile / tiles_n;
  const int tn = tile % tiles_n;

  const int k0 = y * klen;
  const int krem = ktot - k0;
  const int klen_eff = krem < klen ? krem : klen;
  const int nt = klen_eff / BK;

  const size_t coff = (size_t)y * c_split_stride + (size_t)blockIdx.z * c_z_stride;
  if (C)  C  += coff;
  if (Cb) Cb += coff;
  const float* B    = blockIdx.z ? B2 : B1;
  const float* bias = blockIdx.z ? bias2 : bias1;

  const int tid  = threadIdx.x;
  const int lane = tid & 63;
  const int wid  = tid >> 6;
  const int wm = wid >> 1, wn = wid & 1;
  const int l16 = lane & 15, kq = lane >> 4;

  const float* Abase = A + (size_t)(tm * BM) * lda;
  const float* Bbase = B + (size_t)(tn * BN) * ldb;

  f32x4 acc[FM][FN];
  #pragma unroll
  for (int i = 0; i < FM; ++i)
    #pragma unroll
    for (int j = 0; j < FN; ++j)
      acc[i][j] = (f32x4){0.f, 0.f, 0.f, 0.f};

  float4 ra[CHA][2], rb[CHB][2];

  auto loadA = [&](int kk) {
    #pragma unroll
    for (int i = 0; i < CHA; ++i) {
      int ch = tid + i * 256;
      int r = ch / NCH, cc = ch % NCH;
      const float* p = Abase + (size_t)r * lda + kk + cc * 8;
      ra[i][0] = *(const float4*)p;
      ra[i][1] = *(const float4*)(p + 4);
    }
  };
  auto loadB = [&](int kk) {
    #pragma unroll
    for (int i = 0; i < CHB; ++i) {
      int ch = tid + i * 256;
      int r = ch / NCH, cc = ch % NCH;
      const float* p = Bbase + (size_t)r * ldb + kk + cc * 8;
      rb[i][0] = *(const float4*)p;
      rb[i][1] = *(const float4*)(p + 4);
    }
  };
  auto storeAB = [&]() {
    #pragma unroll
    for (int i = 0; i < CHA; ++i) {
      int ch = tid + i * 256;
      int r = ch / NCH, cc = ch % NCH;
      float4 u = ra[i][0], v = ra[i][1];
      short8 s;
      s[0]=f2bf(u.x); s[1]=f2bf(u.y); s[2]=f2bf(u.z); s[3]=f2bf(u.w);
      s[4]=f2bf(v.x); s[5]=f2bf(v.y); s[6]=f2bf(v.z); s[7]=f2bf(v.w);
      *(short8*)&As[r * BKP + cc * 8] = s;
    }
    #pragma unroll
    for (int i = 0; i < CHB; ++i) {
      int ch = tid + i * 256;
      int r = ch / NCH, cc = ch % NCH;
      float4 u = rb[i][0], v = rb[i][1];
      short8 s;
      s[0]=f2bf(u.x); s[1]=f2bf(u.y); s[2]=f2bf(u.z); s[3]=f2bf(u.w);
      s[4]=f2bf(v.x); s[5]=f2bf(v.y); s[6]=f2bf(v.z); s[7]=f2bf(v.w);
      *(short8*)&Bs[r * BKP + cc * 8] = s;
    }
  };

  loadA(k0); loadB(k0);
  storeAB();
  pinned_bar();

  for (int t = 0; t < nt; ++t) {
    if (t + 1 < nt) { loadA(k0 + (t + 1) * BK); loadB(k0 + (t + 1) * BK); }

    #pragma unroll
    for (int ks = 0; ks < BK / 32; ++ks) {
      short8 af[FM], bf[FN];
      #pragma unroll
      for (int i = 0; i < FM; ++i)
        af[i] = *(short8*)&As[(wm * WM + i * 16 + l16) * BKP + ks * 32 + kq * 8];
      #pragma unroll
      for (int j = 0; j < FN; ++j)
        bf[j] = *(short8*)&Bs[(wn * WN + j * 16 + l16) * BKP + ks * 32 + kq * 8];
      #pragma unroll
      for (int i = 0; i < FM; ++i)
        #pragma unroll
        for (int j = 0; j < FN; ++j)
          acc[i][j] = __builtin_amdgcn_mfma_f32_16x16x32_bf16(af[i], bf[j], acc[i][j], 0, 0, 0);
    }

    pinned_bar();                      // reads done; loads stay in flight
    if (t + 1 < nt) storeAB();
    pinned_bar();                      // writes visible
  }

  const int crow0 = tm * BM + wm * WM;
  const int ccol0 = tn * BN + wn * WN;
  #pragma unroll
  for (int i = 0; i < FM; ++i)
    #pragma unroll
    for (int j = 0; j < FN; ++j)
      #pragma unroll
      for (int e = 0; e < 4; ++e) {
        int r = crow0 + i * 16 + kq * 4 + e;
        int c = ccol0 + j * 16 + l16;
        float v = acc[i][j][e];
        if (bias) v += bias[c];
        if (res1) v += res1[(size_t)r * ldc + c];
        if (res2) v += res2[(size_t)r * ldc + c];
        if (do_relu) v = fmaxf(v, 0.f);
        if (Cb) Cb[(size_t)r * ldc + c] = __float2bfloat16(v);
        else    C [(size_t)r * ldc + c] = v;
        if (Ct) Ct[(size_t)c * ldct + r] = v;
      }
}

__global__ __launch_bounds__(256)
void reduce_bias(const __hip_bfloat16* __restrict__ parts, int sk, size_t stride,
                 const float* __restrict__ bias, float* __restrict__ out)
{
  int idx4 = blockIdx.x * 256 + threadIdx.x;
  int c4 = idx4 & (DHID / 4 - 1);
  float4 b = *(const float4*)(bias + (size_t)c4 * 4);
  float s0 = b.x, s1 = b.y, s2 = b.z, s3 = b.w;
  for (int i = 0; i < sk; ++i) {
    const __hip_bfloat16* p = parts + (size_t)i * stride + (size_t)idx4 * 4;
    ushort4 u = *(const ushort4*)p;
    s0 += bf2f(u.x); s1 += bf2f(u.y); s2 += bf2f(u.z); s3 += bf2f(u.w);
  }
  float4 o = {s0, s1, s2, s3};
  *(float4*)(out + (size_t)idx4 * 4) = o;
}

__global__ __launch_bounds__(256)
void transpose_k(const float* __restrict__ in, float* __restrict__ out, int R, int Cc)
{
  __shared__ float t[32][33];
  int bx = blockIdx.x * 32;
  int by = blockIdx.y * 32;
  int tx = threadIdx.x & 31, ty = threadIdx.x >> 5;
  #pragma unroll
  for (int i = 0; i < 4; ++i)
    t[ty + i * 8][tx] = in[(size_t)(by + ty + i * 8) * Cc + bx + tx];
  __syncthreads();
  #pragma unroll
  for (int i = 0; i < 4; ++i)
    out[(size_t)(bx + ty + i * 8) * R + by + tx] = t[tx][ty + i * 8];
}

__global__ __launch_bounds__(256)
void softmax_rows(float* __restrict__ x, float scale)
{
  int row = blockIdx.x;
  float* p = x + (size_t)row * N_PROP;
  int tid = threadIdx.x;
  float a = p[tid] * scale;
  float b = p[tid + 256] * scale;
  float m = fmaxf(a, b);
  #pragma unroll
  for (int o = 32; o > 0; o >>= 1) m = fmaxf(m, __shfl_xor(m, o));
  __shared__ float sm[4], ss[4];
  int w = tid >> 6;
  if ((tid & 63) == 0) sm[w] = m;
  __syncthreads();
  m = fmaxf(fmaxf(sm[0], sm[1]), fmaxf(sm[2], sm[3]));
  float ea = __expf(a - m), eb = __expf(b - m);
  float s = ea + eb;
  #pragma unroll
  for (int o = 32; o > 0; o >>= 1) s += __shfl_xor(s, o);
  if ((tid & 63) == 0) ss[w] = s;
  __syncthreads();
  s = ss[0] + ss[1] + ss[2] + ss[3];
  float inv = 1.f / s;
  p[tid] = ea * inv;
  p[tid + 256] = eb * inv;
}

extern "C" void kernel_launch(void* const* d_in, const int* in_sizes, int n_in,
                              void* d_out, int out_size, void* d_ws, size_t ws_size,
                              hipStream_t stream)
{
  (void)in_sizes; (void)n_in; (void)out_size; (void)ws_size;
  const float* x      = (const float*)d_in[0];
  const float* fc1_w  = (const float*)d_in[1];
  const float* fc1_b  = (const float*)d_in[2];
  const float* fc2_w  = (const float*)d_in[3];
  const float* fc2_b  = (const float*)d_in[4];
  const float* a1w1   = (const float*)d_in[5];
  const float* a1b1   = (const float*)d_in[6];
  const float* a1w2   = (const float*)d_in[7];
  const float* a1b2   = (const float*)d_in[8];
  const float* a1cw   = (const float*)d_in[9];
  const float* a1cb   = (const float*)d_in[10];
  const float* a2w1   = (const float*)d_in[11];
  const float* a2b1   = (const float*)d_in[12];
  const float* a2w2   = (const float*)d_in[13];
  const float* a2b2   = (const float*)d_in[14];
  const float* a2cw   = (const float*)d_in[15];
  const float* a2cb   = (const float*)d_in[16];
  float* out = (float*)d_out;

  char* ws = (char*)d_ws;
  const size_t SZ = (size_t)N_PROP * DHID * 4;      // 2 MB
  float* out0   = (float*)(ws + 0 * SZ);
  float* h0     = (float*)(ws + 1 * SZ);
  float* h1     = (float*)(ws + 2 * SZ);
  float* T      = (float*)(ws + 3 * SZ);
  float* q      = (float*)(ws + 4 * SZ);
  float* k      = (float*)(ws + 5 * SZ);            // adjacent to q (dual-z)
  float* att    = (float*)(ws + 6 * SZ);
  float* logits = (float*)(ws + 7 * SZ);
  __hip_bfloat16* parts =
      (__hip_bfloat16*)(ws + 7 * SZ + (size_t)N_PROP * N_PROP * 4);  // 32 x 1 MB

  const size_t ND = (size_t)N_PROP * DHID;
  const int SK = 32;
  dim3 blk(256);

  // ---- fc1: 256^2 tile, 1024 threads, SK=32 (klen 1568 = 49*32 uniform) ----
  gemm_fc1<<<dim3(8 * SK), dim3(1024), 0, stream>>>(x, fc1_w, parts);
  reduce_bias<<<(N_PROP * DHID) / 1024, blk, 0, stream>>>(parts, SK, ND, fc1_b, out0);

  // ---- attention 1 on out0 ----
  transpose_k<<<dim3(DHID / 32, N_PROP / 32), blk, 0, stream>>>(out0, T, N_PROP, DHID);
  gemm_nt<32, 64, 128, 2><<<dim3(256, 1, 2), blk, 0, stream>>>(
      out0, DHID, a1w1, a1w2, DHID,
      q, nullptr, DHID,
      256, 16, DHID, DHID,
      0, ND,
      a1b1, a1b2, nullptr, nullptr, nullptr, 0, 0);
  gemm_nt<32, 32, 128, 2><<<dim3(256), blk, 0, stream>>>(
      q, DHID, k, nullptr, DHID,
      logits, nullptr, N_PROP,
      256, 16, DHID, DHID,
      0, 0,
      nullptr, nullptr, nullptr, nullptr, nullptr, 0, 0);
  softmax_rows<<<N_PROP, blk, 0, stream>>>(logits, SM_SCALE);
  gemm_nt<32, 64, 128, 2><<<dim3(256), blk, 0, stream>>>(
      logits, N_PROP, T, nullptr, N_PROP,
      att, nullptr, DHID,
      256, 16, N_PROP, N_PROP,
      0, 0,
      nullptr, nullptr, nullptr, nullptr, nullptr, 0, 0);
  gemm_nt<32, 64, 128, 2><<<dim3(256), blk, 0, stream>>>(
      att, DHID, a1cw, nullptr, DHID,
      h0, nullptr, DHID,
      256, 16, DHID, DHID,
      0, 0,
      a1cb, nullptr, out0, nullptr, nullptr, 0, 1);
  gemm_nt<32, 64, 128, 2><<<dim3(256), blk, 0, stream>>>(
      h0, DHID, fc2_w, nullptr, DHID,
      h1, nullptr, DHID,
      256, 16, DHID, DHID,
      0, 0,
      fc2_b, nullptr, nullptr, nullptr, T, N_PROP, 0);

  // ---- attention 2 on h1 ----
  gemm_nt<32, 64, 128, 2><<<dim3(256, 1, 2), blk, 0, stream>>>(
      h1, DHID, a2w1, a2w2, DHID,
      q, nullptr, DHID,
      256, 16, DHID, DHID,
      0, ND,
      a2b1, a2b2, nullptr, nullptr, nullptr, 0, 0);
  gemm_nt<32, 32, 128, 2><<<dim3(256), blk, 0, stream>>>(
      q, DHID, k, nullptr, DHID,
      logits, nullptr, N_PROP,
      256, 16, DHID, DHID,
      0, 0,
      nullptr, nullptr, nullptr, nullptr, nullptr, 0, 0);
  softmax_rows<<<N_PROP, blk, 0, stream>>>(logits, SM_SCALE);
  gemm_nt<32, 64, 128, 2><<<dim3(256), blk, 0, stream>>>(
      logits, N_PROP, T, nullptr, N_PROP,
      att, nullptr, DHID,
      256, 16, N_PROP, N_PROP,
      0, 0,
      nullptr, nullptr, nullptr, nullptr, nullptr, 0, 0);
  gemm_nt<32, 64, 128, 2><<<dim3(256), blk, 0, stream>>>(
      att, DHID, a2cw, nullptr, DHID,
      out, nullptr, DHID,
      256, 16, DHID, DHID,
      0, 0,
      a2cb, nullptr, h1, out0, nullptr, 0, 1);
}